// Round 7
// baseline (478.279 us; speedup 1.0000x reference)
//
#include <hip/hip_runtime.h>
#include <stdint.h>

// Correlation_29609504538974: 6-level spatial correlation, patch 3x3 + leaky_relu(corr/C).
// out_l[b, t, y, x] = leaky( (1/C) * sum_c f1[b,c,y,x] * f2[b,c,y+di,x+dj] ),
//   t=(di+1)*3+(dj+1); f1 = x_l, f2 = x_pre_l. Zero pad outside.
//
// R11: R10 (quad 12 B/px, depth-2, (512,4)) ran clean (no spill) but flat at
// 150 us: delivered load-bytes rate fell to 6.8 B/cy/CU (67% of the ~10.2
// empirical per-CU vector-memory ceiling; R7 hit 91%). Occupancy is capped at
// 50% (VGPR>64 -> 4 waves/SIMD -> 2 blocks/CU) and can't rise with 36 accs.
// Fix: deepen per-wave MLP instead: 4-buffer prefetch-distance-3 pipeline
// (12-18 loads = 6-9 KB in flight per wave, 3x the latency tolerance of
// depth-2). Regs ~100+slack < 128 cap -> no spill (tripwire: WRITE_SIZE).
// Everything else identical to R10: 2x2 quad per lane (f1 2 rows + 4 staged f2
// rows = 12 B/px-ch issued), 8-wave channel split, LDS reduce in two 128-px
// half-phases (36 KB), ws partials + fin, shuffle dj=+-1 taps (garbage only
// feeds store-masked taps), adaptive chunks (all modes give csize mult-of-4,
// >=8, so the pipeline prologue/epilogue is exact with no overrun).

struct Lv {
  const float* f1;
  const float* f2;
  float* dst;        // partial base (ws region, or out region in fallback)
  int C, ss, csize;  // channels, log2(S), channels per wave
  uint32_t tiles;    // quad tiles (nquads/64, ceil)
  uint32_t nquads;   // npix/4
  uint32_t blk_end;  // cumulative block count
};
struct P { Lv lv[6]; };

struct Fv {
  const float* src;
  uint32_t end;      // cumulative out element end
  uint32_t cstride;  // 9*npix
  uint32_t nchunk;
  int ss;
  float invC;
};
struct PF { Fv f[6]; uint32_t total; };

#define LOADIT(A0, A1, R0, R1, R2, R3)   \
  do {                                   \
    (A0) = *(const float2*)(f1b + o1);   \
    (A1) = *(const float2*)(f1b + o2);   \
    (R0) = *(const float2*)(f2b + o0);   \
    (R1) = *(const float2*)(f2b + o1);   \
    (R2) = *(const float2*)(f2b + o2);   \
    (R3) = *(const float2*)(f2b + o3);   \
    f1b += S2;                           \
    f2b += S2;                           \
  } while (0)

// prev lane's .y == f2[x0-1]; next lane's .x == f2[x0+2]. All shuffle garbage
// (row/image/tile edges, clamped tail lanes) only feeds taps masked in corr_fin:
// lane layout guarantees x0==0 at every shfl_up discontinuity and x0==S-2 at
// every shfl_down discontinuity (qpi and tile sizes are multiples of quads/row).
#define FMAIT(A0, A1, R0, R1, R2, R3)                              \
  do {                                                             \
    const float2 rr_[4] = {R0, R1, R2, R3};                        \
    float pw_[4], nx_[4];                                          \
    _Pragma("unroll") for (int m_ = 0; m_ < 4; ++m_) {             \
      pw_[m_] = __shfl_up(rr_[m_].y, 1);                           \
      nx_[m_] = __shfl_down(rr_[m_].x, 1);                         \
    }                                                              \
    _Pragma("unroll") for (int r_ = 0; r_ < 2; ++r_) {             \
      const float2 a_ = r_ ? (A1) : (A0);                          \
      _Pragma("unroll") for (int d_ = 0; d_ < 3; ++d_) {           \
        const float2 R_ = rr_[r_ + d_];                            \
        const float p_ = pw_[r_ + d_], n_ = nx_[r_ + d_];          \
        acc[r_][d_][0][0] = fmaf(a_.x, p_, acc[r_][d_][0][0]);     \
        acc[r_][d_][0][1] = fmaf(a_.y, R_.x, acc[r_][d_][0][1]);   \
        acc[r_][d_][1][0] = fmaf(a_.x, R_.x, acc[r_][d_][1][0]);   \
        acc[r_][d_][1][1] = fmaf(a_.y, R_.y, acc[r_][d_][1][1]);   \
        acc[r_][d_][2][0] = fmaf(a_.x, R_.y, acc[r_][d_][2][0]);   \
        acc[r_][d_][2][1] = fmaf(a_.y, n_, acc[r_][d_][2][1]);     \
      }                                                            \
    }                                                              \
  } while (0)

#define LD0 LOADIT(a00, a01, u0, v0, w0, z0)
#define LD1 LOADIT(a10, a11, u1, v1, w1, z1)
#define LD2 LOADIT(a20, a21, u2, v2, w2, z2)
#define LD3 LOADIT(a30, a31, u3, v3, w3, z3)
#define FM0 FMAIT(a00, a01, u0, v0, w0, z0)
#define FM1 FMAIT(a10, a11, u1, v1, w1, z1)
#define FM2 FMAIT(a20, a21, u2, v2, w2, z2)
#define FM3 FMAIT(a30, a31, u3, v3, w3, z3)

__global__ __launch_bounds__(512, 4) void corr_part(P p) {
  __shared__ float red[8][9 * 128];  // 36 KB

  const uint32_t bid = blockIdx.x;
  int l = 0;
#pragma unroll
  for (int i = 0; i < 5; ++i) l += (bid >= p.lv[i].blk_end) ? 1 : 0;
  const Lv L = p.lv[l];
  const uint32_t local = bid - (l ? p.lv[l - 1].blk_end : 0u);
  const uint32_t chunk = local / L.tiles;  // chunk-major: tile-neighbors adjacent
  const uint32_t tile = local - chunk * L.tiles;

  const int w = (int)(threadIdx.x >> 6);
  const int lane = (int)(threadIdx.x & 63u);
  const int ss = L.ss;
  const int S = 1 << ss;
  const int S2 = 1 << (2 * ss);
  const uint32_t qpiM = (1u << (2 * ss - 2)) - 1u;  // quads-per-image - 1
  const uint32_t qrwM = (1u << (ss - 1)) - 1u;      // quads-per-row - 1

  uint32_t g = tile * 64u + (uint32_t)lane;  // global quad id
  if (g >= L.nquads) g = L.nquads - 1u;      // tail lanes: garbage, stores masked
  const uint32_t b = g >> (2 * ss - 2);
  const uint32_t qyx = g & qpiM;
  const int y0 = (int)((qyx >> (ss - 1)) << 1);

  const uint32_t c0 = chunk * (uint32_t)(8 * L.csize) + (uint32_t)(w * L.csize);
  const size_t pbase = ((size_t)(b * (uint32_t)L.C + c0)) << (2 * ss);
  const float* __restrict__ f1b = L.f1 + pbase;
  const float* __restrict__ f2b = L.f2 + pbase;

  const int ym = (y0 - 1) < 0 ? 0 : (y0 - 1);          // clamped; taps masked in fin
  const int yp = (y0 + 2) > (S - 1) ? (S - 1) : (y0 + 2);
  const int xb = (int)((qyx & qrwM) << 1);
  const int o0 = ym * S + xb;
  const int o1 = y0 * S + xb;
  const int o2 = o1 + S;        // y0+1 always < S
  const int o3 = yp * S + xb;

  float acc[2][3][3][2];  // [outrow][rowtap][coltap][e]
#pragma unroll
  for (int r = 0; r < 2; ++r)
#pragma unroll
    for (int d = 0; d < 3; ++d)
#pragma unroll
      for (int dd = 0; dd < 3; ++dd) {
        acc[r][d][dd][0] = 0.f;
        acc[r][d][dd][1] = 0.f;
      }

  // 4-buffer, prefetch-distance-3 software pipeline.
  // Requires n % 4 == 0 and n >= 8 (true for every level in every ws mode):
  // prologue loads ch 0,1; each trip loads 4 / consumes 4; epilogue loads the
  // final 2 and consumes 4 -- exactly n channels, no overrun.
  const int n = L.csize;
  float2 a00, a01, u0, v0, w0, z0;
  float2 a10, a11, u1, v1, w1, z1;
  float2 a20, a21, u2, v2, w2, z2;
  float2 a30, a31, u3, v3, w3, z3;
  LD0;
  LD1;
#pragma unroll 1
  for (int j = 0; j + 6 < n; j += 4) {
    LD2; FM0;
    LD3; FM1;
    LD0; FM2;
    LD1; FM3;
  }
  LD2; FM0;
  LD3; FM1;
  FM2;
  FM3;

  // Two half-phases: lanes 0..31's quads (128 px), then lanes 32..63's.
  float* dbase = L.dst + (size_t)chunk * 9u * ((size_t)L.nquads << 2);
#pragma unroll
  for (int h = 0; h < 2; ++h) {
    if ((lane >> 5) == h) {
      const int q = lane & 31;
#pragma unroll
      for (int r = 0; r < 2; ++r)
#pragma unroll
        for (int d = 0; d < 3; ++d)
#pragma unroll
          for (int dd = 0; dd < 3; ++dd) {
            const int t = d * 3 + dd;
            *(float2*)&red[w][t * 128 + q * 4 + r * 2] =
                make_float2(acc[r][d][dd][0], acc[r][d][dd][1]);
          }
    }
    __syncthreads();
    for (int idx = (int)threadIdx.x; idx < 9 * 128; idx += 512) {
      float s = 0.f;
#pragma unroll
      for (int ww = 0; ww < 8; ++ww) s += red[ww][idx];
      const int t = idx >> 7;
      const int pl = idx & 127;
      const uint32_t g2 = tile * 64u + (uint32_t)(h * 32) + (uint32_t)(pl >> 2);
      if (g2 < L.nquads) {
        const int k = pl & 3;
        const uint32_t b2 = g2 >> (2 * ss - 2);
        const uint32_t qyx2 = g2 & qpiM;
        const int yy = (int)((qyx2 >> (ss - 1)) << 1) + (k >> 1);
        const int xx = (int)((qyx2 & qrwM) << 1) + (k & 1);
        dbase[(((size_t)(b2 * 9u + (uint32_t)t)) << (2 * ss)) +
              (uint32_t)(yy * S + xx)] = s;
      }
    }
    __syncthreads();
  }
}

__global__ __launch_bounds__(256) void corr_fin(PF p, float* __restrict__ out) {
  const uint32_t e = blockIdx.x * 256u + threadIdx.x;
  if (e >= p.total) return;
  int l = 0;
#pragma unroll
  for (int i = 0; i < 5; ++i) l += (e >= p.f[i].end) ? 1 : 0;
  const Fv F = p.f[l];
  const int ss = F.ss;
  const int S = 1 << ss;
  const int S2 = 1 << (2 * ss);
  const uint32_t local = e - (F.end - F.cstride);
  const uint32_t bt = local >> (2 * ss);
  const uint32_t yx = local & (uint32_t)(S2 - 1);
  const uint32_t t = bt % 9u;  // constant div -> magic mul
  const int y = (int)(yx >> ss);
  const int x = (int)(yx & (uint32_t)(S - 1));
  const int di = (int)t / 3 - 1;
  const int dj = (int)t % 3 - 1;
  const int qy = y + di;
  const int qx = x + dj;

  float s = 0.f;
  for (uint32_t k = 0; k < F.nchunk; ++k) s += F.src[(size_t)k * F.cstride + local];

  float v = 0.f;
  if ((qy >= 0) & (qy < S) & (qx >= 0) & (qx < S)) {
    v = s * F.invC;
    v = v >= 0.f ? v : 0.01f * v;
  }
  out[e] = v;
}

extern "C" void kernel_launch(void* const* d_in, const int* in_sizes, int n_in,
                              void* d_out, int out_size, void* d_ws, size_t ws_size,
                              hipStream_t stream) {
  static const int CH[6] = {512, 1024, 512, 256, 256, 256};
  static const int LG[6] = {6, 5, 4, 3, 2, 1};
  static const int BASE[6] = {2, 4, 2, 1, 1, 1};  // chunk base (7.4 MB)

  // setup_inputs() dict order is interleaved: d_in[2i]=x_pre_i, d_in[2i+1]=x_i.
  const bool interleaved = (n_in >= 2) && (in_sizes[0] == in_sizes[1]);

  uint32_t npixs[6], ooff[6], oacc = 0;
  for (int i = 0; i < 6; ++i) {
    npixs[i] = 16u << (2 * LG[i]);
    ooff[i] = oacc;
    oacc += 9u * npixs[i];
  }

  // Adaptive chunk multiplier: m=2 (1612 blocks, uniform 16 iters/wave) if ws
  // fits, else m=1 (806), else fallback chunk=1 writing raw sums into out.
  // All modes: csize multiple of 4 and >= 8 (pipeline requirement).
  size_t need1 = 0;
  for (int i = 0; i < 6; ++i) need1 += (size_t)BASE[i] * 9u * npixs[i];
  need1 *= sizeof(float);
  const size_t need2 = need1 * 2u;
  int mode;  // 2, 1, or 0 (fallback)
  if (d_ws && ws_size >= need2) mode = 2;
  else if (d_ws && ws_size >= need1) mode = 1;
  else mode = 0;

  int NCK[6];
  for (int i = 0; i < 6; ++i) NCK[i] = (mode == 0) ? 1 : BASE[i] * mode;

  P p;
  PF pf;
  float* ws = (float*)d_ws;
  float* out = (float*)d_out;
  uint32_t bend = 0;
  size_t woff = 0;
  for (int i = 0; i < 6; ++i) {
    const uint32_t nquads = npixs[i] >> 2;
    const uint32_t tiles = (nquads + 63u) / 64u;
    Lv& L = p.lv[i];
    L.f1 = (const float*)d_in[interleaved ? (2 * i + 1) : (6 + i)];
    L.f2 = (const float*)d_in[interleaved ? (2 * i) : i];
    L.dst = (mode == 0) ? (out + ooff[i]) : (ws + woff);
    L.C = CH[i];
    L.ss = LG[i];
    L.csize = CH[i] / (8 * NCK[i]);
    L.tiles = tiles;
    L.nquads = nquads;
    bend += tiles * (uint32_t)NCK[i];
    L.blk_end = bend;

    Fv& F = pf.f[i];
    F.src = L.dst;
    F.end = ooff[i] + 9u * npixs[i];
    F.cstride = 9u * npixs[i];
    F.nchunk = (uint32_t)NCK[i];
    F.ss = LG[i];
    F.invC = 1.0f / (float)CH[i];
    woff += (size_t)NCK[i] * 9u * npixs[i];
  }
  pf.total = oacc;

  corr_part<<<bend, 512, 0, stream>>>(p);
  corr_fin<<<(oacc + 255u) / 256u, 256, 0, stream>>>(pf, out);
}

// Round 8
// 397.778 us; speedup vs baseline: 1.2024x; 1.2024x over previous
//
#include <hip/hip_runtime.h>
#include <stdint.h>

// Correlation_29609504538974: 6-level spatial correlation, patch 3x3 + leaky_relu(corr/C).
// out_l[b, t, y, x] = leaky( (1/C) * sum_c f1[b,c,y,x] * f2[b,c,y+di,x+dj] ),
//   t=(di+1)*3+(dj+1); f1 = x_l, f2 = x_pre_l. Zero pad outside.
//
// R12: R11 (4-buffer ring) spilled (WRITE 388 MB vs 21; ran AT the ~10.2 B/cy/CU
// memory-pipe ceiling but wasted 55% on scratch). Lever = issued bytes at
// CONSTANT register pressure. Change vs R10: VERTICAL HALO EXCHANGE.
// Quad lanes within a wave share the channel, and lane-Q (Q = S/2 quads/row)
// holds f2 row y0-1 in its o2 register, lane+Q holds y0+2 in its o1. So load
// only f2 rows o1,o2 (unique); derive o0/o3 via 4 __shfl + cndmask; only
// wave-boundary lanes (lane<Q / lane>=64-Q, row in-image) load 1 halo row.
// Waves are image-aligned at every level -> all invalid shuffles land in taps
// corr_fin masks (y0==0 / y0+2==S), same discipline as the x-shuffles.
// Issued: L0 10 B/px, L1 9, L2-L5 8 (whole image per wave, zero halo) ->
// 504 MB vs R10's 633 (-20%). Buffers shrink 12->10 floats; depth-2 pipeline
// kept verbatim from R10 (proven no-spill). Tripwire: WRITE_SIZE ~21 MB.

struct Lv {
  const float* f1;
  const float* f2;
  float* dst;        // partial base (ws region, or out region in fallback)
  int C, ss, csize;  // channels, log2(S), channels per wave
  uint32_t tiles;    // quad tiles (nquads/64, ceil)
  uint32_t nquads;   // npix/4
  uint32_t blk_end;  // cumulative block count
};
struct P { Lv lv[6]; };

struct Fv {
  const float* src;
  uint32_t end;      // cumulative out element end
  uint32_t cstride;  // 9*npix
  uint32_t nchunk;
  int ss;
  float invC;
};
struct PF { Fv f[6]; uint32_t total; };

#define LOADIT(A0, A1, R1, R2, H)                    \
  do {                                               \
    (A0) = *(const float2*)(f1b + o1);               \
    (A1) = *(const float2*)(f1b + o2);               \
    (R1) = *(const float2*)(f2b + o1);               \
    (R2) = *(const float2*)(f2b + o2);               \
    if (needH) (H) = *(const float2*)(f2b + oh);     \
    f1b += S2;                                       \
    f2b += S2;                                       \
  } while (0)

// Row derivation: o0 = shfl(R2, lane-Q) (lane-Q's y0+1 == this y0-1), or the
// loaded halo H for wave-top lanes; o3 = shfl(R1, lane+Q) or H for wave-bottom.
// x taps: prev lane's .y == f2[x0-1]; next lane's .x == f2[x0+2]. ALL shuffle
// garbage (image/wave/tile edges, clamped tail lanes) feeds only taps masked in
// corr_fin (x0==0 / x0==S-2 at x-discontinuities; y0==0 / y0+2==S at vertical).
#define FMAIT(A0, A1, R1, R2, H)                                   \
  do {                                                             \
    float2 sT_, sB_, r0_, r3_;                                     \
    sT_.x = __shfl((R2).x, iu);                                    \
    sT_.y = __shfl((R2).y, iu);                                    \
    sB_.x = __shfl((R1).x, ib);                                    \
    sB_.y = __shfl((R1).y, ib);                                    \
    r0_.x = needT ? (H).x : sT_.x;                                 \
    r0_.y = needT ? (H).y : sT_.y;                                 \
    r3_.x = needB ? (H).x : sB_.x;                                 \
    r3_.y = needB ? (H).y : sB_.y;                                 \
    const float2 rr_[4] = {r0_, (R1), (R2), r3_};                  \
    float pw_[4], nx_[4];                                          \
    _Pragma("unroll") for (int m_ = 0; m_ < 4; ++m_) {             \
      pw_[m_] = __shfl_up(rr_[m_].y, 1);                           \
      nx_[m_] = __shfl_down(rr_[m_].x, 1);                         \
    }                                                              \
    _Pragma("unroll") for (int r_ = 0; r_ < 2; ++r_) {             \
      const float2 a_ = r_ ? (A1) : (A0);                          \
      _Pragma("unroll") for (int d_ = 0; d_ < 3; ++d_) {           \
        const float2 R_ = rr_[r_ + d_];                            \
        const float p_ = pw_[r_ + d_], n_ = nx_[r_ + d_];          \
        acc[r_][d_][0][0] = fmaf(a_.x, p_, acc[r_][d_][0][0]);     \
        acc[r_][d_][0][1] = fmaf(a_.y, R_.x, acc[r_][d_][0][1]);   \
        acc[r_][d_][1][0] = fmaf(a_.x, R_.x, acc[r_][d_][1][0]);   \
        acc[r_][d_][1][1] = fmaf(a_.y, R_.y, acc[r_][d_][1][1]);   \
        acc[r_][d_][2][0] = fmaf(a_.x, R_.y, acc[r_][d_][2][0]);   \
        acc[r_][d_][2][1] = fmaf(a_.y, n_, acc[r_][d_][2][1]);     \
      }                                                            \
    }                                                              \
  } while (0)

__global__ __launch_bounds__(512, 4) void corr_part(P p) {
  __shared__ float red[8][9 * 128];  // 36 KB

  const uint32_t bid = blockIdx.x;
  int l = 0;
#pragma unroll
  for (int i = 0; i < 5; ++i) l += (bid >= p.lv[i].blk_end) ? 1 : 0;
  const Lv L = p.lv[l];
  const uint32_t local = bid - (l ? p.lv[l - 1].blk_end : 0u);
  const uint32_t chunk = local / L.tiles;  // chunk-major: tile-neighbors adjacent
  const uint32_t tile = local - chunk * L.tiles;

  const int w = (int)(threadIdx.x >> 6);
  const int lane = (int)(threadIdx.x & 63u);
  const int ss = L.ss;
  const int S = 1 << ss;
  const int S2 = 1 << (2 * ss);
  const uint32_t qpiM = (1u << (2 * ss - 2)) - 1u;  // quads-per-image - 1
  const uint32_t qrwM = (1u << (ss - 1)) - 1u;      // quads-per-row - 1

  uint32_t g = tile * 64u + (uint32_t)lane;  // global quad id
  if (g >= L.nquads) g = L.nquads - 1u;      // tail lanes: garbage, stores masked
  const uint32_t b = g >> (2 * ss - 2);
  const uint32_t qyx = g & qpiM;
  const int y0 = (int)((qyx >> (ss - 1)) << 1);
  const int xb = (int)((qyx & qrwM) << 1);

  const uint32_t c0 = chunk * (uint32_t)(8 * L.csize) + (uint32_t)(w * L.csize);
  const size_t pbase = ((size_t)(b * (uint32_t)L.C + c0)) << (2 * ss);
  const float* __restrict__ f1b = L.f1 + pbase;
  const float* __restrict__ f2b = L.f2 + pbase;

  const int Q = S >> 1;                  // quads per pixel-row (1..32)
  const int iu = lane - Q;               // vertical-up shfl source
  const int ib = lane + Q;               // vertical-down shfl source
  const bool needT = (lane < Q) && (y0 > 0);         // wave-top, row in-image
  const bool needB = (lane >= 64 - Q) && (y0 + 2 < S);  // wave-bottom (disjoint)
  const bool needH = needT || needB;
  const int o1 = y0 * S + xb;
  const int o2 = o1 + S;                 // y0+1 always < S
  const int oh = needT ? (o1 - S) : (o2 + S);  // guarded by needH

  float acc[2][3][3][2];  // [outrow][rowtap][coltap][e]
#pragma unroll
  for (int r = 0; r < 2; ++r)
#pragma unroll
    for (int d = 0; d < 3; ++d)
#pragma unroll
      for (int dd = 0; dd < 3; ++dd) {
        acc[r][d][dd][0] = 0.f;
        acc[r][d][dd][1] = 0.f;
      }

  // Depth-2 software pipeline (R10-proven) over n channel-iters (n even >= 2).
  const int n = L.csize;
  float2 a00, a01, p0, q0, h0;
  float2 a10, a11, p1, q1, h1;
  h0 = make_float2(0.f, 0.f);
  h1 = h0;
  LOADIT(a00, a01, p0, q0, h0);
#pragma unroll 1
  for (int j = 0; j + 2 < n; j += 2) {
    LOADIT(a10, a11, p1, q1, h1);
    FMAIT(a00, a01, p0, q0, h0);
    LOADIT(a00, a01, p0, q0, h0);
    FMAIT(a10, a11, p1, q1, h1);
  }
  LOADIT(a10, a11, p1, q1, h1);
  FMAIT(a00, a01, p0, q0, h0);
  FMAIT(a10, a11, p1, q1, h1);

  // Two half-phases: lanes 0..31's quads (128 px), then lanes 32..63's.
  float* dbase = L.dst + (size_t)chunk * 9u * ((size_t)L.nquads << 2);
#pragma unroll
  for (int h = 0; h < 2; ++h) {
    if ((lane >> 5) == h) {
      const int q = lane & 31;
#pragma unroll
      for (int r = 0; r < 2; ++r)
#pragma unroll
        for (int d = 0; d < 3; ++d)
#pragma unroll
          for (int dd = 0; dd < 3; ++dd) {
            const int t = d * 3 + dd;
            *(float2*)&red[w][t * 128 + q * 4 + r * 2] =
                make_float2(acc[r][d][dd][0], acc[r][d][dd][1]);
          }
    }
    __syncthreads();
    for (int idx = (int)threadIdx.x; idx < 9 * 128; idx += 512) {
      float s = 0.f;
#pragma unroll
      for (int ww = 0; ww < 8; ++ww) s += red[ww][idx];
      const int t = idx >> 7;
      const int pl = idx & 127;
      const uint32_t g2 = tile * 64u + (uint32_t)(h * 32) + (uint32_t)(pl >> 2);
      if (g2 < L.nquads) {
        const int k = pl & 3;
        const uint32_t b2 = g2 >> (2 * ss - 2);
        const uint32_t qyx2 = g2 & qpiM;
        const int yy = (int)((qyx2 >> (ss - 1)) << 1) + (k >> 1);
        const int xx = (int)((qyx2 & qrwM) << 1) + (k & 1);
        dbase[(((size_t)(b2 * 9u + (uint32_t)t)) << (2 * ss)) +
              (uint32_t)(yy * S + xx)] = s;
      }
    }
    __syncthreads();
  }
}

__global__ __launch_bounds__(256) void corr_fin(PF p, float* __restrict__ out) {
  const uint32_t e = blockIdx.x * 256u + threadIdx.x;
  if (e >= p.total) return;
  int l = 0;
#pragma unroll
  for (int i = 0; i < 5; ++i) l += (e >= p.f[i].end) ? 1 : 0;
  const Fv F = p.f[l];
  const int ss = F.ss;
  const int S = 1 << ss;
  const int S2 = 1 << (2 * ss);
  const uint32_t local = e - (F.end - F.cstride);
  const uint32_t bt = local >> (2 * ss);
  const uint32_t yx = local & (uint32_t)(S2 - 1);
  const uint32_t t = bt % 9u;  // constant div -> magic mul
  const int y = (int)(yx >> ss);
  const int x = (int)(yx & (uint32_t)(S - 1));
  const int di = (int)t / 3 - 1;
  const int dj = (int)t % 3 - 1;
  const int qy = y + di;
  const int qx = x + dj;

  float s = 0.f;
  for (uint32_t k = 0; k < F.nchunk; ++k) s += F.src[(size_t)k * F.cstride + local];

  float v = 0.f;
  if ((qy >= 0) & (qy < S) & (qx >= 0) & (qx < S)) {
    v = s * F.invC;
    v = v >= 0.f ? v : 0.01f * v;
  }
  out[e] = v;
}

extern "C" void kernel_launch(void* const* d_in, const int* in_sizes, int n_in,
                              void* d_out, int out_size, void* d_ws, size_t ws_size,
                              hipStream_t stream) {
  static const int CH[6] = {512, 1024, 512, 256, 256, 256};
  static const int LG[6] = {6, 5, 4, 3, 2, 1};
  static const int BASE[6] = {2, 4, 2, 1, 1, 1};  // chunk base (7.4 MB)

  // setup_inputs() dict order is interleaved: d_in[2i]=x_pre_i, d_in[2i+1]=x_i.
  const bool interleaved = (n_in >= 2) && (in_sizes[0] == in_sizes[1]);

  uint32_t npixs[6], ooff[6], oacc = 0;
  for (int i = 0; i < 6; ++i) {
    npixs[i] = 16u << (2 * LG[i]);
    ooff[i] = oacc;
    oacc += 9u * npixs[i];
  }

  // Adaptive chunk multiplier: m=2 (1612 blocks, uniform 16 iters/wave) if ws
  // fits, else m=1 (806), else fallback chunk=1 writing raw sums into out.
  // All modes: csize even and >= 2 (depth-2 pipeline requirement).
  size_t need1 = 0;
  for (int i = 0; i < 6; ++i) need1 += (size_t)BASE[i] * 9u * npixs[i];
  need1 *= sizeof(float);
  const size_t need2 = need1 * 2u;
  int mode;  // 2, 1, or 0 (fallback)
  if (d_ws && ws_size >= need2) mode = 2;
  else if (d_ws && ws_size >= need1) mode = 1;
  else mode = 0;

  int NCK[6];
  for (int i = 0; i < 6; ++i) NCK[i] = (mode == 0) ? 1 : BASE[i] * mode;

  P p;
  PF pf;
  float* ws = (float*)d_ws;
  float* out = (float*)d_out;
  uint32_t bend = 0;
  size_t woff = 0;
  for (int i = 0; i < 6; ++i) {
    const uint32_t nquads = npixs[i] >> 2;
    const uint32_t tiles = (nquads + 63u) / 64u;
    Lv& L = p.lv[i];
    L.f1 = (const float*)d_in[interleaved ? (2 * i + 1) : (6 + i)];
    L.f2 = (const float*)d_in[interleaved ? (2 * i) : i];
    L.dst = (mode == 0) ? (out + ooff[i]) : (ws + woff);
    L.C = CH[i];
    L.ss = LG[i];
    L.csize = CH[i] / (8 * NCK[i]);
    L.tiles = tiles;
    L.nquads = nquads;
    bend += tiles * (uint32_t)NCK[i];
    L.blk_end = bend;

    Fv& F = pf.f[i];
    F.src = L.dst;
    F.end = ooff[i] + 9u * npixs[i];
    F.cstride = 9u * npixs[i];
    F.nchunk = (uint32_t)NCK[i];
    F.ss = LG[i];
    F.invC = 1.0f / (float)CH[i];
    woff += (size_t)NCK[i] * 9u * npixs[i];
  }
  pf.total = oacc;

  corr_part<<<bend, 512, 0, stream>>>(p);
  corr_fin<<<(oacc + 255u) / 256u, 256, 0, stream>>>(pf, out);
}